// Round 6
// baseline (37.289 us; speedup 1.0000x reference)
//
#include <hip/hip_runtime.h>

// LocalSelfAttention: bs=4, h=12, s=4096, d=64, BLOCK=64 -> 3072 independent
// 64x64x64 block-attention problems. fp32 in/out.
// R0 35.9 / R2 36.6 / R3 36.3 / R4 36.0 us. Falsified: occupancy (32-55%),
// barriers (2/1), pipelining, LDS conflicts (3.15M->0.39M), spills.
// Model: stream-bound at 201 MB logical / 36us = 5.6 TB/s = 89% of copy
// ceiling. R5: last copy-asymmetry -- O stores were 16 scalar dwords/thread
// (MFMA D-layout is column-wise). Route O via 16KB LDS tile -> 4x
// global_store_dwordx4 per thread (1KB/wave-instr), else identical to R4.

typedef __attribute__((ext_vector_type(8))) short bf16x8;   // 8 bf16 = 4 VGPR
typedef __attribute__((ext_vector_type(4))) float f32x4;    // MFMA 16x16 acc
typedef __attribute__((ext_vector_type(4))) unsigned short us4; // 8B LDS store

#define MFMA16(a, b, c) __builtin_amdgcn_mfma_f32_16x16x32_bf16((a), (b), (c), 0, 0, 0)
// XOR swizzle for K tile (bf16, 128B rows).
#define SWZ(byteoff, row) ((byteoff) ^ (((row) & 7) << 4))
// XOR swizzle for O tile (fp32, 256B rows): rows 4 apart -> different 64B
// group; residual 2-way (rows 8 apart) is free (m136).
#define SWZO(byteoff, row) ((byteoff) ^ (((row) & 7) << 4))

static __device__ __forceinline__ unsigned short f2bf(float x) {
    union { float f; unsigned int u; } v; v.f = x;
    unsigned int r = v.u + 0x7fffu + ((v.u >> 16) & 1u);   // RNE
    return (unsigned short)(r >> 16);
}
static __device__ __forceinline__ float bf2f(unsigned short b) {
    union { float f; unsigned int u; } v; v.u = ((unsigned int)b) << 16;
    return v.f;
}

__global__ __launch_bounds__(256) void lsa_kernel(
    const float* __restrict__ Q, const float* __restrict__ K,
    const float* __restrict__ V, const float* __restrict__ M,
    float* __restrict__ O)
{
    __shared__ unsigned short Kh[4096];   // K bf16 hi [key][d], swizzled
    __shared__ unsigned short Kl[4096];   // K bf16 lo
    __shared__ float Of[4096];            // O fp32 [q][d], swizzled
    __shared__ float maskv[64];

    const int tid  = threadIdx.x;
    const int gid  = blockIdx.x;
    const size_t base = (size_t)gid * 4096;

    const int lane = tid & 63;
    const int wv   = tid >> 6;
    const int cc   = lane & 15;
    const int gg   = lane >> 4;
    const int qrow = wv * 16 + cc;

    // ---- issue K staging loads + Q fragment loads ----
    const float4* Kg = (const float4*)(K + base);
    float4 kv[4];
#pragma unroll
    for (int it = 0; it < 4; ++it) kv[it] = Kg[tid + it * 256];

    bf16x8 qfh[2], qfl[2];
#pragma unroll
    for (int s = 0; s < 2; ++s) {
        const float* qp = Q + base + (size_t)qrow * 64 + s * 32 + gg * 8;
        float4 f0 = *(const float4*)qp;
        float4 f1 = *(const float4*)(qp + 4);
        float f[8] = {f0.x, f0.y, f0.z, f0.w, f1.x, f1.y, f1.z, f1.w};
        bf16x8 h, l;
#pragma unroll
        for (int j = 0; j < 8; ++j) {
            unsigned short hb = f2bf(f[j]);
            h[j] = (short)hb;
            l[j] = (short)f2bf(f[j] - bf2f(hb));
        }
        qfh[s] = h; qfl[s] = l;
    }
    if (tid < 64) {
        int b = gid / 768;
        int blk = gid & 63;
        maskv[tid] = M[(size_t)b * 4096 + blk * 64 + tid];
    }

    // ---- stage K hi/lo into LDS (8B stores, swizzled) ----
#pragma unroll
    for (int it = 0; it < 4; ++it) {
        int i   = tid + it * 256;
        int row = i >> 4;
        int cb  = (i & 15) * 8;
        float4 x = kv[it];
        us4 h, l;
        unsigned short hb;
        hb = f2bf(x.x); h.x = hb; l.x = f2bf(x.x - bf2f(hb));
        hb = f2bf(x.y); h.y = hb; l.y = f2bf(x.y - bf2f(hb));
        hb = f2bf(x.z); h.z = hb; l.z = f2bf(x.z - bf2f(hb));
        hb = f2bf(x.w); h.w = hb; l.w = f2bf(x.w - bf2f(hb));
        int by = SWZ(row * 128 + cb, row);
        *(us4*)((char*)Kh + by) = h;
        *(us4*)((char*)Kl + by) = l;
    }
    __syncthreads();

    // ---- S^T = K·Q^T (hi/lo 3-term); C: col=cc=q, key-local=gg*4+reg ----
    float sc[16];
#pragma unroll
    for (int kt = 0; kt < 4; ++kt) {
        f32x4 acc = {0.f, 0.f, 0.f, 0.f};
        int krow = kt * 16 + cc;
#pragma unroll
        for (int s = 0; s < 2; ++s) {
            int by = SWZ(krow * 128 + s * 64 + gg * 16, krow);
            bf16x8 ah = *(bf16x8*)((char*)Kh + by);
            bf16x8 al = *(bf16x8*)((char*)Kl + by);
            acc = MFMA16(ah, qfh[s], acc);
            acc = MFMA16(ah, qfl[s], acc);
            acc = MFMA16(al, qfh[s], acc);
        }
#pragma unroll
        for (int r = 0; r < 4; ++r) sc[kt * 4 + r] = acc[r];
    }

    // ---- prefetch V frags for dt=0 while softmax runs ----
    const float* Vb = V + base;
    float vf[16], vn[16];
    {
        const float* p0 = Vb + (size_t)(gg * 8) * 64 + cc;
        const float* p1 = Vb + (size_t)(32 + gg * 8) * 64 + cc;
#pragma unroll
        for (int j = 0; j < 8; ++j) { vf[j] = p0[j * 64]; vf[8 + j] = p1[j * 64]; }
    }

    // ---- mask + softmax ----
    float mx = -3.0e38f;
#pragma unroll
    for (int kt = 0; kt < 4; ++kt)
#pragma unroll
        for (int r = 0; r < 4; ++r) {
            int key = kt * 16 + gg * 4 + r;
            float sv = sc[kt * 4 + r] + (maskv[key] == 0.f ? -10000.f : 0.f);
            sc[kt * 4 + r] = sv;
            mx = fmaxf(mx, sv);
        }
    mx = fmaxf(mx, __shfl_xor(mx, 16));
    mx = fmaxf(mx, __shfl_xor(mx, 32));
    float sum = 0.f;
#pragma unroll
    for (int i = 0; i < 16; ++i) { sc[i] = __expf(sc[i] - mx); sum += sc[i]; }
    sum += __shfl_xor(sum, 16);
    sum += __shfl_xor(sum, 32);
    float inv = (maskv[qrow] == 0.f ? 0.f : 1.f) / sum;

    // ---- P re-fragmentation in-wave (R1 derivation) ----
    unsigned int pku[8];
#pragma unroll
    for (int kt = 0; kt < 4; ++kt) {
        unsigned int e0 = f2bf(sc[kt * 4 + 0] * inv);
        unsigned int e1 = f2bf(sc[kt * 4 + 1] * inv);
        unsigned int e2 = f2bf(sc[kt * 4 + 2] * inv);
        unsigned int e3 = f2bf(sc[kt * 4 + 3] * inv);
        pku[kt * 2 + 0] = e0 | (e1 << 16);
        pku[kt * 2 + 1] = e2 | (e3 << 16);
    }
    const int src0 = ((2 * gg) & 3) * 16 + cc;
    const int src1 = ((2 * gg + 1) & 3) * 16 + cc;
    const bool sel = (gg >> 1) & 1;
    bf16x8 pf[2];
#pragma unroll
    for (int s = 0; s < 2; ++s) {
        unsigned int a0 = (unsigned)__shfl((int)pku[4 * s + 0], src0);
        unsigned int a1 = (unsigned)__shfl((int)pku[4 * s + 1], src0);
        unsigned int b0 = (unsigned)__shfl((int)pku[4 * s + 2], src0);
        unsigned int b1 = (unsigned)__shfl((int)pku[4 * s + 3], src0);
        unsigned int c0 = (unsigned)__shfl((int)pku[4 * s + 0], src1);
        unsigned int c1 = (unsigned)__shfl((int)pku[4 * s + 1], src1);
        unsigned int d0 = (unsigned)__shfl((int)pku[4 * s + 2], src1);
        unsigned int d1 = (unsigned)__shfl((int)pku[4 * s + 3], src1);
        union { unsigned int w[4]; bf16x8 v; } u;
        u.w[0] = sel ? b0 : a0;
        u.w[1] = sel ? b1 : a1;
        u.w[2] = sel ? d0 : c0;
        u.w[3] = sel ? d1 : c1;
        pf[s] = u.v;
    }

    // ---- O = P·V; D-frags go to LDS (own slots, no race) ----
#pragma unroll
    for (int dt = 0; dt < 4; ++dt) {
        if (dt < 3) {
            const float* p0 = Vb + (size_t)(gg * 8) * 64 + (dt + 1) * 16 + cc;
            const float* p1 = Vb + (size_t)(32 + gg * 8) * 64 + (dt + 1) * 16 + cc;
#pragma unroll
            for (int j = 0; j < 8; ++j) { vn[j] = p0[j * 64]; vn[8 + j] = p1[j * 64]; }
        }
        bf16x8 vb0, vb1;
#pragma unroll
        for (int j = 0; j < 8; ++j) {
            vb0[j] = (short)f2bf(vf[j]);
            vb1[j] = (short)f2bf(vf[8 + j]);
        }
        f32x4 o = {0.f, 0.f, 0.f, 0.f};
        o = MFMA16(pf[0], vb0, o);
        o = MFMA16(pf[1], vb1, o);
#pragma unroll
        for (int r = 0; r < 4; ++r) {
            int q = wv * 16 + gg * 4 + r;
            int by = SWZO(q * 256 + (dt * 16 + cc) * 4, q);
            *(float*)((char*)Of + by) = o[r];
        }
#pragma unroll
        for (int j = 0; j < 16; ++j) vf[j] = vn[j];
    }
    __syncthreads();   // O tile complete

    // ---- copy-grade store: 4x dwordx4 per thread, 1KB/wave-instr ----
    float* Ob = O + base;
#pragma unroll
    for (int it = 0; it < 4; ++it) {
        int i   = tid + it * 256;     // float4 slot 0..1023
        int row = i >> 4;
        int f4  = i & 15;
        float4 val = *(float4*)((char*)Of + SWZO(row * 256 + f4 * 16, row));
        *(float4*)(Ob + (size_t)row * 64 + f4 * 4) = val;
    }
}

extern "C" void kernel_launch(void* const* d_in, const int* in_sizes, int n_in,
                              void* d_out, int out_size, void* d_ws, size_t ws_size,
                              hipStream_t stream) {
    const float* Q = (const float*)d_in[0];
    const float* K = (const float*)d_in[1];
    const float* V = (const float*)d_in[2];
    const float* M = (const float*)d_in[3];
    float* O = (float*)d_out;
    int grid = in_sizes[0] / 4096;   // 3072
    lsa_kernel<<<grid, 256, 0, stream>>>(Q, K, V, M, O);
}

// Round 7
// 35.738 us; speedup vs baseline: 1.0434x; 1.0434x over previous
//
#include <hip/hip_runtime.h>

// LocalSelfAttention: bs=4, h=12, s=4096, d=64, BLOCK=64 -> 3072 independent
// 64x64x64 block-attention problems. fp32 in/out.
// FINAL (= R4, best of 6 variants at 35.96us).
// Falsified levers: occupancy 32-55% (R0/R2/R3), barriers 2/1 (R2),
// persistent+pipelined WGs (R3), LDS bank conflicts 3.15M->0.39M (R4),
// spills (R1), store width via LDS round-trip (R5, regressed).
// Roofline: 201 MB irreducible traffic / 36us = 5.6 TB/s = 89% of the
// 6.29 TB/s copy ceiling (123 MB HBM + ~78 MB L3-served). Memory-bound.

typedef __attribute__((ext_vector_type(8))) short bf16x8;   // 8 bf16 = 4 VGPR
typedef __attribute__((ext_vector_type(4))) float f32x4;    // MFMA 16x16 acc
typedef __attribute__((ext_vector_type(4))) unsigned short us4; // 8B LDS store

#define MFMA16(a, b, c) __builtin_amdgcn_mfma_f32_16x16x32_bf16((a), (b), (c), 0, 0, 0)
// XOR swizzle (guide §6 G4) for the K tile (row stride 128B).
#define SWZ(byteoff, row) ((byteoff) ^ (((row) & 7) << 4))

static __device__ __forceinline__ unsigned short f2bf(float x) {
    union { float f; unsigned int u; } v; v.f = x;
    unsigned int r = v.u + 0x7fffu + ((v.u >> 16) & 1u);   // RNE
    return (unsigned short)(r >> 16);
}
static __device__ __forceinline__ float bf2f(unsigned short b) {
    union { float f; unsigned int u; } v; v.u = ((unsigned int)b) << 16;
    return v.f;
}

// One WG (4 waves) per (b,h,block); wave = 16-query strip.
// S^T = K·Q^T (bf16 hi/lo split for fp32-grade scores); softmax in-lane +
// 2 shuffles; P re-frag by 16 in-wave shuffles; PV B-operand straight from
// global (16-lane-contiguous, L1/L2-resident, one-dt-ahead prefetch).
__global__ __launch_bounds__(256) void lsa_kernel(
    const float* __restrict__ Q, const float* __restrict__ K,
    const float* __restrict__ V, const float* __restrict__ M,
    float* __restrict__ O)
{
    __shared__ unsigned short Kh[4096];   // K bf16 hi [key][d], swizzled
    __shared__ unsigned short Kl[4096];   // K bf16 lo
    __shared__ float maskv[64];

    const int tid  = threadIdx.x;
    const int gid  = blockIdx.x;
    const size_t base = (size_t)gid * 4096;

    const int lane = tid & 63;
    const int wv   = tid >> 6;
    const int cc   = lane & 15;
    const int gg   = lane >> 4;
    const int qrow = wv * 16 + cc;

    // ---- issue K staging loads + Q fragment loads ----
    const float4* Kg = (const float4*)(K + base);
    float4 kv[4];
#pragma unroll
    for (int it = 0; it < 4; ++it) kv[it] = Kg[tid + it * 256];

    bf16x8 qfh[2], qfl[2];
#pragma unroll
    for (int s = 0; s < 2; ++s) {
        const float* qp = Q + base + (size_t)qrow * 64 + s * 32 + gg * 8;
        float4 f0 = *(const float4*)qp;
        float4 f1 = *(const float4*)(qp + 4);
        float f[8] = {f0.x, f0.y, f0.z, f0.w, f1.x, f1.y, f1.z, f1.w};
        bf16x8 h, l;
#pragma unroll
        for (int j = 0; j < 8; ++j) {
            unsigned short hb = f2bf(f[j]);
            h[j] = (short)hb;
            l[j] = (short)f2bf(f[j] - bf2f(hb));
        }
        qfh[s] = h; qfl[s] = l;
    }
    if (tid < 64) {
        int b = gid / 768;
        int blk = gid & 63;
        maskv[tid] = M[(size_t)b * 4096 + blk * 64 + tid];
    }

    // ---- stage K hi/lo into LDS (8B stores, swizzled, conflict-free) ----
#pragma unroll
    for (int it = 0; it < 4; ++it) {
        int i   = tid + it * 256;
        int row = i >> 4;
        int cb  = (i & 15) * 8;
        float4 x = kv[it];
        us4 h, l;
        unsigned short hb;
        hb = f2bf(x.x); h.x = hb; l.x = f2bf(x.x - bf2f(hb));
        hb = f2bf(x.y); h.y = hb; l.y = f2bf(x.y - bf2f(hb));
        hb = f2bf(x.z); h.z = hb; l.z = f2bf(x.z - bf2f(hb));
        hb = f2bf(x.w); h.w = hb; l.w = f2bf(x.w - bf2f(hb));
        int by = SWZ(row * 128 + cb, row);
        *(us4*)((char*)Kh + by) = h;
        *(us4*)((char*)Kl + by) = l;
    }
    __syncthreads();   // the only barrier

    // ---- S^T = K·Q^T (hi/lo 3-term); C: col=cc=q, key-local=gg*4+reg ----
    float sc[16];
#pragma unroll
    for (int kt = 0; kt < 4; ++kt) {
        f32x4 acc = {0.f, 0.f, 0.f, 0.f};
        int krow = kt * 16 + cc;
#pragma unroll
        for (int s = 0; s < 2; ++s) {
            int by = SWZ(krow * 128 + s * 64 + gg * 16, krow);
            bf16x8 ah = *(bf16x8*)((char*)Kh + by);
            bf16x8 al = *(bf16x8*)((char*)Kl + by);
            acc = MFMA16(ah, qfh[s], acc);
            acc = MFMA16(ah, qfl[s], acc);
            acc = MFMA16(al, qfh[s], acc);
        }
#pragma unroll
        for (int r = 0; r < 4; ++r) sc[kt * 4 + r] = acc[r];
    }

    // ---- prefetch V frags for dt=0 while softmax runs ----
    // B-frag element j (of half s) = V[s*32+gg*8+j][dt*16+cc]:
    // 16-lane contiguous, j-stride 64 floats -> imm offsets.
    const float* Vb = V + base;
    float vf[16], vn[16];
    {
        const float* p0 = Vb + (size_t)(0 * 32 + gg * 8) * 64 + 0 * 16 + cc;
        const float* p1 = Vb + (size_t)(1 * 32 + gg * 8) * 64 + 0 * 16 + cc;
#pragma unroll
        for (int j = 0; j < 8; ++j) { vf[j] = p0[j * 64]; vf[8 + j] = p1[j * 64]; }
    }

    // ---- mask + softmax (lane: one query, 16 of 64 keys) ----
    float mx = -3.0e38f;
#pragma unroll
    for (int kt = 0; kt < 4; ++kt)
#pragma unroll
        for (int r = 0; r < 4; ++r) {
            int key = kt * 16 + gg * 4 + r;
            float sv = sc[kt * 4 + r] + (maskv[key] == 0.f ? -10000.f : 0.f);
            sc[kt * 4 + r] = sv;
            mx = fmaxf(mx, sv);
        }
    mx = fmaxf(mx, __shfl_xor(mx, 16));
    mx = fmaxf(mx, __shfl_xor(mx, 32));
    float sum = 0.f;
#pragma unroll
    for (int i = 0; i < 16; ++i) { sc[i] = __expf(sc[i] - mx); sum += sc[i]; }
    sum += __shfl_xor(sum, 16);
    sum += __shfl_xor(sum, 32);
    float inv = (maskv[qrow] == 0.f ? 0.f : 1.f) / sum;

    // ---- P re-fragmentation in-wave (R1 derivation) ----
    unsigned int pku[8];
#pragma unroll
    for (int kt = 0; kt < 4; ++kt) {
        unsigned int e0 = f2bf(sc[kt * 4 + 0] * inv);
        unsigned int e1 = f2bf(sc[kt * 4 + 1] * inv);
        unsigned int e2 = f2bf(sc[kt * 4 + 2] * inv);
        unsigned int e3 = f2bf(sc[kt * 4 + 3] * inv);
        pku[kt * 2 + 0] = e0 | (e1 << 16);
        pku[kt * 2 + 1] = e2 | (e3 << 16);
    }
    const int src0 = ((2 * gg) & 3) * 16 + cc;
    const int src1 = ((2 * gg + 1) & 3) * 16 + cc;
    const bool sel = (gg >> 1) & 1;
    bf16x8 pf[2];
#pragma unroll
    for (int s = 0; s < 2; ++s) {
        unsigned int a0 = (unsigned)__shfl((int)pku[4 * s + 0], src0);
        unsigned int a1 = (unsigned)__shfl((int)pku[4 * s + 1], src0);
        unsigned int b0 = (unsigned)__shfl((int)pku[4 * s + 2], src0);
        unsigned int b1 = (unsigned)__shfl((int)pku[4 * s + 3], src0);
        unsigned int c0 = (unsigned)__shfl((int)pku[4 * s + 0], src1);
        unsigned int c1 = (unsigned)__shfl((int)pku[4 * s + 1], src1);
        unsigned int d0 = (unsigned)__shfl((int)pku[4 * s + 2], src1);
        unsigned int d1 = (unsigned)__shfl((int)pku[4 * s + 3], src1);
        union { unsigned int w[4]; bf16x8 v; } u;
        u.w[0] = sel ? b0 : a0;
        u.w[1] = sel ? b1 : a1;
        u.w[2] = sel ? d0 : c0;
        u.w[3] = sel ? d1 : c1;
        pf[s] = u.v;
    }

    // ---- O = P·V, V frags from global, one-dt-ahead prefetch ----
    float* Ob = O + base;
#pragma unroll
    for (int dt = 0; dt < 4; ++dt) {
        if (dt < 3) {
            const float* p0 = Vb + (size_t)(0 * 32 + gg * 8) * 64 + (dt + 1) * 16 + cc;
            const float* p1 = Vb + (size_t)(1 * 32 + gg * 8) * 64 + (dt + 1) * 16 + cc;
#pragma unroll
            for (int j = 0; j < 8; ++j) { vn[j] = p0[j * 64]; vn[8 + j] = p1[j * 64]; }
        }
        bf16x8 vb0, vb1;
#pragma unroll
        for (int j = 0; j < 8; ++j) {
            vb0[j] = (short)f2bf(vf[j]);
            vb1[j] = (short)f2bf(vf[8 + j]);
        }
        f32x4 o = {0.f, 0.f, 0.f, 0.f};
        o = MFMA16(pf[0], vb0, o);
        o = MFMA16(pf[1], vb1, o);
#pragma unroll
        for (int r = 0; r < 4; ++r) {
            int q = wv * 16 + gg * 4 + r;
            Ob[q * 64 + dt * 16 + cc] = o[r];
        }
#pragma unroll
        for (int j = 0; j < 16; ++j) vf[j] = vn[j];   // SSA-renamed, free
    }
}

extern "C" void kernel_launch(void* const* d_in, const int* in_sizes, int n_in,
                              void* d_out, int out_size, void* d_ws, size_t ws_size,
                              hipStream_t stream) {
    const float* Q = (const float*)d_in[0];
    const float* K = (const float*)d_in[1];
    const float* V = (const float*)d_in[2];
    const float* M = (const float*)d_in[3];
    float* O = (float*)d_out;
    int grid = in_sizes[0] / 4096;   // 3072
    lsa_kernel<<<grid, 256, 0, stream>>>(Q, K, V, M, O);
}